// Round 4
// baseline (4519.486 us; speedup 1.0000x reference)
//
#include <hip/hip_runtime.h>
#include <stdint.h>

#define DEVFN __device__ __forceinline__

typedef __attribute__((ext_vector_type(4))) float fx4;
typedef __attribute__((ext_vector_type(8))) short sx8;
typedef __bf16 bf16x8 __attribute__((ext_vector_type(8)));

DEVFN float eluf(float x){ return x>0.f ? x : __expf(x)-1.f; }
DEVFN float sigm(float x){ return 1.f/(1.f+__expf(-x)); }
DEVFN float tanhf_(float x){ float cx=fminf(10.f,fmaxf(-10.f,x)); float e=__expf(-2.f*cx); return (1.f-e)/(1.f+e); }

DEVFN fx4 MFMA(sx8 a, sx8 b, fx4 c){
  return __builtin_amdgcn_mfma_f32_16x16x32_bf16(
      __builtin_bit_cast(bf16x8,a), __builtin_bit_cast(bf16x8,b), c, 0,0,0);
}
DEVFN void splitf(float x, short& hi, short& lo){
  __bf16 h = (__bf16)x; hi = __builtin_bit_cast(short, h);
  __bf16 l = (__bf16)(x - (float)h); lo = __builtin_bit_cast(short, l);
}

// ---------------- prep kernels ----------------
struct TT { const float* src; float* dst; int srows, scols, drows; };
struct TTs { TT t[4]; };
__global__ void k_prep_t(TTs ts){   // dst[c][r] = src[r][c], zero-pad c>=scols
  TT tk = ts.t[blockIdx.y];
  size_t tot = (size_t)tk.drows * tk.srows;
  for (size_t i = (size_t)blockIdx.x*256 + threadIdx.x; i < tot; i += (size_t)gridDim.x*256){
    int c = (int)(i / tk.srows), r = (int)(i % tk.srows);
    tk.dst[i] = (c < tk.scols) ? tk.src[(size_t)r*tk.scols + c] : 0.f;
  }
}
struct PL { const float* src; __bf16* hi; __bf16* lo; size_t n; };
struct PLs { PL t[2]; };
__global__ void k_prep_planes(PLs ts){
  PL tk = ts.t[blockIdx.y];
  for (size_t i = (size_t)blockIdx.x*256 + threadIdx.x; i < tk.n; i += (size_t)gridDim.x*256){
    float x = tk.src[i];
    __bf16 h = (__bf16)x;
    tk.hi[i] = h; tk.lo[i] = (__bf16)(x - (float)h);
  }
}
struct BC { const float* src; __bf16* dst; size_t n; };
struct BCs { BC t[2]; };
__global__ void k_prep_b16(BCs ts){
  BC tk = ts.t[blockIdx.y];
  for (size_t i = (size_t)blockIdx.x*256 + threadIdx.x; i < tk.n; i += (size_t)gridDim.x*256)
    tk.dst[i] = (__bf16)tk.src[i];
}

// ------- split-precision GEMM: out[m][n] = sum_k A[m][k]*B[n][k], f32 in -------
// EPI: 0 none, 1 +bias, 2 +bias+elu ; OBF: 1 -> bf16 out, else f32
template<int EPI, int OBF>
__global__ __launch_bounds__(256) void gemm_k(
    const float* __restrict__ A, const float* __restrict__ B,
    const float* __restrict__ bias, void* __restrict__ out,
    int M, int N, int Kpad, int Kreal, int lda, int ldb)
{
  int bm = blockIdx.x*64, bn = blockIdx.y*64;
  int tid = threadIdx.x, l = tid&63, w = tid>>6;
  int wm = (w>>1)*32, wn = (w&1)*32;
  int lr = l&15, lk = l>>4;
  fx4 acc[2][2] = {};
  for (int k0 = 0; k0 < Kpad; k0 += 32) {
    sx8 ahi[2], alo[2], bhi[2], blo[2];
    bool full = (k0 + 32 <= Kreal);
    #pragma unroll
    for (int i=0;i<2;i++){
      int row = bm + wm + i*16 + lr; row = row < M ? row : M-1;
      int col = bn + wn + i*16 + lr;
      const float* ap = A + (size_t)row*lda + k0 + lk*8;
      const float* bp = B + (size_t)col*ldb + k0 + lk*8;
      float av[8], bv[8];
      if (full){
        *(fx4*)av = *(const fx4*)ap; *(fx4*)(av+4) = *(const fx4*)(ap+4);
        *(fx4*)bv = *(const fx4*)bp; *(fx4*)(bv+4) = *(const fx4*)(bp+4);
      } else {
        #pragma unroll
        for (int j=0;j<8;j++){
          int k = k0 + lk*8 + j;
          av[j] = (k < Kreal) ? ap[j] : 0.f;
          bv[j] = (k < Kreal) ? bp[j] : 0.f;
        }
      }
      #pragma unroll
      for (int j=0;j<8;j++){
        short h,lo2; splitf(av[j], h, lo2); ahi[i][j]=h; alo[i][j]=lo2;
        splitf(bv[j], h, lo2); bhi[i][j]=h; blo[i][j]=lo2;
      }
    }
    #pragma unroll
    for (int i=0;i<2;i++)
      #pragma unroll
      for (int j=0;j<2;j++){
        acc[i][j] = MFMA(alo[i], bhi[j], acc[i][j]);
        acc[i][j] = MFMA(ahi[i], blo[j], acc[i][j]);
        acc[i][j] = MFMA(ahi[i], bhi[j], acc[i][j]);
      }
  }
  #pragma unroll
  for (int i=0;i<2;i++)
    #pragma unroll
    for (int j=0;j<2;j++)
      #pragma unroll
      for (int q=0;q<4;q++){
        int m = bm + wm + i*16 + lk*4 + q;
        int n = bn + wn + j*16 + lr;
        if (m < M){
          float v = acc[i][j][q];
          if (EPI>=1) v += bias[n];
          if (EPI==2) v = eluf(v);
          if (OBF) ((__bf16*)out)[(size_t)m*N + n] = (__bf16)v;
          else     ((float*)out)[(size_t)m*N + n] = v;
        }
      }
}

// -------- dn BiGRU: 352 WGs x 32 chains, 512 thr (8 waves), split precision --------
// T reads + seqh writes are nontemporal so W_hh (hi/lo, 1.57 MB) stays L2-resident.
__global__ __launch_bounds__(512,2) void dn_gru(
  const float* __restrict__ T,                 // [20000][768] f32
  const __bf16* __restrict__ Whi, const __bf16* __restrict__ Wlo,  // [768][256]
  const float* __restrict__ bh,
  const int* __restrict__ ents, const int* __restrict__ locs,
  const int* __restrict__ wrl, const int* __restrict__ cmd,
  float* __restrict__ seqh, int dir)
{
  __shared__ __align__(16) __bf16 hhi[32*256];  // swizzled: (m,k)-> m*256 + ((k>>3 ^ (m&31))<<3 | (k&7))
  __shared__ __align__(16) __bf16 hlo[32*256];
  __shared__ int toks[32];
  int wg = blockIdx.x;
  int cb = wg*32;
  int tid = threadIdx.x, l = tid&63, wn = tid>>6;   // 8 waves; wave wn owns j in [wn*32, wn*32+32)
  int lr = l&15, lk = l>>4;
  float bR[2], bZ[2], bN[2];
  #pragma unroll
  for (int jb=0;jb<2;jb++){
    int j = wn*32 + jb*16 + lr;
    bR[jb]=bh[j]; bZ[jb]=bh[256+j]; bN[jb]=bh[512+j];
  }
  for (int i=tid;i<32*256;i+=512){ hhi[i]=(__bf16)0.f; hlo[i]=(__bf16)0.f; }
  for (int s=0;s<16;s++){
    __syncthreads();
    if (tid<32){
      int c = cb+tid; const int* tp;
      if (c<1024) tp = ents + c*16;
      else if (c<2048) tp = locs + (c-1024)*16;
      else if (c<10240) tp = wrl + (c-2048)*16;
      else tp = cmd + (c-10240)*16;
      toks[tid] = tp[dir? 15-s : s];
    }
    __syncthreads();
    fx4 acc[2][6] = {};
    for (int kk=0;kk<8;kk++){
      sx8 ah[2], al[2];
      #pragma unroll
      for (int mt=0;mt<2;mt++){
        int row = mt*16 + lr;
        int c = (kk*4+lk) ^ (row&31);
        ah[mt] = *(const sx8*)&hhi[row*256 + c*8];
        al[mt] = *(const sx8*)&hlo[row*256 + c*8];
      }
      #pragma unroll
      for (int jb=0;jb<2;jb++)
        #pragma unroll
        for (int role=0;role<3;role++){
          int col = role*256 + wn*32 + jb*16 + lr;
          sx8 bh_ = *(const sx8*)(Whi + (size_t)col*256 + kk*32 + lk*8);
          sx8 bl_ = *(const sx8*)(Wlo + (size_t)col*256 + kk*32 + lk*8);
          #pragma unroll
          for (int mt=0;mt<2;mt++){
            fx4 a = acc[mt][jb*3+role];
            a = MFMA(al[mt], bh_, a);
            a = MFMA(ah[mt], bl_, a);
            a = MFMA(ah[mt], bh_, a);
            acc[mt][jb*3+role] = a;
          }
        }
    }
    float hnew[2][4][2];
    #pragma unroll
    for (int mt=0;mt<2;mt++){
      #pragma unroll
      for (int q=0;q<4;q++){
        int m = mt*16 + lk*4 + q;
        const float* trow = T + (size_t)toks[m]*768;
        #pragma unroll
        for (int jb=0;jb<2;jb++){
          int j = wn*32 + jb*16 + lr;
          float hr = acc[mt][jb*3+0][q] + bR[jb];
          float hz = acc[mt][jb*3+1][q] + bZ[jb];
          float hn = acc[mt][jb*3+2][q] + bN[jb];
          float xr = __builtin_nontemporal_load(trow + j);
          float xz = __builtin_nontemporal_load(trow + 256 + j);
          float xn = __builtin_nontemporal_load(trow + 512 + j);
          int cc = ((j>>3) ^ (m&31));
          int hidx = m*256 + cc*8 + (j&7);
          float ho = (float)hhi[hidx] + (float)hlo[hidx];
          float r = sigm(xr+hr), z = sigm(xz+hz);
          float n = tanhf_(xn + r*hn);
          hnew[mt][q][jb] = (1.f-z)*n + z*ho;
        }
      }
    }
    if (s < 15){
      __syncthreads();
      #pragma unroll
      for (int mt=0;mt<2;mt++)
        #pragma unroll
        for (int q=0;q<4;q++)
          #pragma unroll
          for (int jb=0;jb<2;jb++){
            int m = mt*16 + lk*4 + q;
            int j = wn*32 + jb*16 + lr;
            int cc = ((j>>3) ^ (m&31));
            int hidx = m*256 + cc*8 + (j&7);
            float v = hnew[mt][q][jb];
            __bf16 h = (__bf16)v;
            hhi[hidx] = h; hlo[hidx] = (__bf16)(v - (float)h);
          }
    } else {
      #pragma unroll
      for (int mt=0;mt<2;mt++)
        #pragma unroll
        for (int q=0;q<4;q++)
          #pragma unroll
          for (int jb=0;jb<2;jb++){
            int m = mt*16 + lk*4 + q;
            int j = wn*32 + jb*16 + lr;
            __builtin_nontemporal_store(hnew[mt][q][jb], &seqh[(size_t)(cb+m)*512 + dir*256 + j]);
          }
    }
  }
}

// ---------------- worlds sum / rowsum / combine (f32) ----------------
__global__ void k_wsum(const float* __restrict__ seqh, float* __restrict__ ws){
  int r = blockIdx.x;
  for (int c = threadIdx.x; c < 512; c += 256){
    float a = 0.f;
    #pragma unroll
    for (int w8=0; w8<8; w8++) a += seqh[((size_t)2048 + r*8 + w8)*512 + c];
    ws[(size_t)r*512 + c] = a;
  }
}
__global__ void k_rowsum(const float* __restrict__ seqh, float* __restrict__ rs){
  int r = blockIdx.x, l = threadIdx.x;  // 64 threads
  float a = 0.f;
  for (int c=l;c<512;c+=64) a += seqh[(size_t)r*512+c];
  #pragma unroll
  for (int o=32;o>0;o>>=1) a += __shfl_down(a,o);
  if (l==0) rs[r]=a;
}
__global__ void k_combine(const float* __restrict__ E1, const float* __restrict__ E2,
                          const float* __restrict__ E3, const float* __restrict__ rs,
                          float* __restrict__ y){
  size_t i = (size_t)blockIdx.x*256 + threadIdx.x;  // grid 2048 -> 524288 exact
  int r = (int)(i >> 9);
  float g = eluf(E1[i] + rs[r]) + eluf(E2[i]) + E3[i];
  y[i] = eluf(g);
}

// ------- persistent diff BiGRU: 16 WGs (dir*8+seg), 64 steps, atomic barrier -------
__global__ __launch_bounds__(256) void diff_all(
  float* __restrict__ hA, float* __restrict__ hB,
  const __bf16* __restrict__ Whf, const __bf16* __restrict__ Whb,
  const float* __restrict__ bhf, const float* __restrict__ bhb,
  const __bf16* __restrict__ Xf, const __bf16* __restrict__ Xb,
  unsigned* __restrict__ bar)
{
  int wg = blockIdx.x;           // 16: dir*8 + seg
  int dir = wg>>3, seg = wg&7;
  const __bf16* W = dir? Whb: Whf;
  const float* bh = dir? bhb: bhf;
  const __bf16* X = dir? Xb: Xf;
  int tid = threadIdx.x, l = tid&63, w = tid>>6;
  int lr=l&15, lk=l>>4;
  int jbase = seg*64 + w*16;
  int j = jbase + lr;
  float bRv = bh[j], bZv = bh[512+j], bNv = bh[1024+j];
  float* hsrc = hA; float* hdst = hB;
  for (int t=0; t<64; ++t){
    int tt = dir? 63-t : t;
    fx4 acc[3] = {};
    const float* hrow = hsrc + (size_t)dir*16*512;
    for (int kk=0;kk<16;kk++){
      const float* ap = hrow + (size_t)lr*512 + kk*32 + lk*8;
      float av[8];
      *(fx4*)av = *(const fx4*)ap; *(fx4*)(av+4) = *(const fx4*)(ap+4);
      sx8 ah, al;
      #pragma unroll
      for (int jj=0;jj<8;jj++){ short h,lo; splitf(av[jj],h,lo); ah[jj]=h; al[jj]=lo; }
      #pragma unroll
      for (int role=0;role<3;role++){
        int col = role*512 + jbase + lr;
        sx8 b = *(const sx8*)(W + (size_t)col*512 + kk*32 + lk*8);
        acc[role] = MFMA(al, b, acc[role]);
        acc[role] = MFMA(ah, b, acc[role]);
      }
    }
    #pragma unroll
    for (int q=0;q<4;q++){
      int m = lk*4+q;
      float hr = acc[0][q] + bRv;
      float hz = acc[1][q] + bZv;
      float hn = acc[2][q] + bNv;
      const __bf16* xrow = X + ((size_t)m*64 + tt)*1536;
      float xr = (float)xrow[j], xz = (float)xrow[512+j], xn = (float)xrow[1024+j];
      float ho = hrow[(size_t)m*512 + j];
      float r = sigm(xr+hr), z = sigm(xz+hz);
      float n = tanhf_(xn + r*hn);
      hdst[((size_t)dir*16 + m)*512 + j] = (1.f-z)*n + z*ho;
    }
    // device-scope barrier across the 16 co-resident WGs
    __threadfence();          // make this thread's h stores visible device-wide
    __syncthreads();          // all threads of WG have fenced
    if (tid==0){
      atomicAdd(bar, 1u);     // device scope by default
      unsigned target = 16u*(unsigned)(t+1);
      while (__hip_atomic_load(bar, __ATOMIC_RELAXED, __HIP_MEMORY_SCOPE_AGENT) < target)
        __builtin_amdgcn_s_sleep(2);
    }
    __syncthreads();
    __threadfence();          // acquire: invalidate stale L1 before reading others' h
    float* tmp = hsrc; hsrc = hdst; hdst = tmp;
  }
}

// ---------------- scoring ----------------
__global__ __launch_bounds__(256) void k_score(
  const float* __restrict__ Amat, const float* __restrict__ Gmat,
  const float* __restrict__ Wa2, const float* __restrict__ ba2, float* __restrict__ sc)
{
  __shared__ float red[4];
  int p = blockIdx.x, b = p>>6, tid = threadIdx.x;
  float av[4], wv[4];
  #pragma unroll
  for (int k=0;k<4;k++){ av[k] = Amat[(size_t)p*1024 + tid + k*256]; wv[k] = Wa2[tid + k*256]; }
  float acc = 0.f;
  for (int n=0;n<64;n++){
    const float* g = Gmat + ((size_t)b*64+n)*1024;
    #pragma unroll
    for (int k=0;k<4;k++) acc += wv[k]*eluf(av[k] + g[tid + k*256]);
  }
  #pragma unroll
  for (int o=32;o>0;o>>=1) acc += __shfl_down(acc,o);
  if ((tid&63)==0) red[tid>>6] = acc;
  __syncthreads();
  if (tid==0) sc[p] = (red[0]+red[1]+red[2]+red[3])*(1.f/64.f) + ba2[0];
}

__global__ void k_final(const float* __restrict__ sc, const int* __restrict__ cmds,
                        const float* __restrict__ hfin, const float* __restrict__ Wc,
                        const float* __restrict__ bc, float* __restrict__ out)
{
  int b = blockIdx.x, l = threadIdx.x;   // 64 threads
  out[b*64+l] = sc[b*64+l];
  int ssum = 0;
  const int* cr = cmds + (b*64+l)*16;
  #pragma unroll
  for (int k=0;k<16;k++) ssum += cr[k];
  float v = ssum>0 ? sc[b*64+l] : -1e9f;
  int idx = l;
  #pragma unroll
  for (int o=32;o>0;o>>=1){
    float ov = __shfl_down(v,o); int oi = __shfl_down(idx,o);
    if (ov > v || (ov==v && oi<idx)) { v=ov; idx=oi; }
  }
  if (l==0) out[1024 + b] = (float)idx;
  float a = 0.f;
  for (int j=l;j<512;j+=64) a += hfin[(size_t)b*512+j] * Wc[j];
  for (int j=l;j<512;j+=64) a += hfin[(size_t)(16+b)*512+j] * Wc[512+j];
  #pragma unroll
  for (int o=32;o>0;o>>=1) a += __shfl_down(a,o);
  if (l==0) out[1040 + b] = a + bc[0];
}

// ---------------- host ----------------
static inline void launch_gemm(hipStream_t st, const float* A, const float* B,
                               const float* bias, void* out, int M, int N,
                               int Kpad, int Kreal, int lda, int ldb, int epi, int obf)
{
  dim3 g((M+63)/64, N/64), blk(256);
  if      (epi==0 && obf==0) gemm_k<0,0><<<g,blk,0,st>>>(A,B,bias,out,M,N,Kpad,Kreal,lda,ldb);
  else if (epi==1 && obf==0) gemm_k<1,0><<<g,blk,0,st>>>(A,B,bias,out,M,N,Kpad,Kreal,lda,ldb);
  else if (epi==2 && obf==0) gemm_k<2,0><<<g,blk,0,st>>>(A,B,bias,out,M,N,Kpad,Kreal,lda,ldb);
  else                       gemm_k<1,1><<<g,blk,0,st>>>(A,B,bias,out,M,N,Kpad,Kreal,lda,ldb);
}

extern "C" void kernel_launch(void* const* d_in, const int* in_sizes, int n_in,
                              void* d_out, int out_size, void* d_ws, size_t ws_size,
                              hipStream_t stream) {
  (void)in_sizes; (void)n_in; (void)out_size; (void)ws_size;
  const float* emb   = (const float*)d_in[0];
  const float* W_prj = (const float*)d_in[1];
  const float* dnWif = (const float*)d_in[2];
  const float* dnWhf = (const float*)d_in[3];
  const float* dnbif = (const float*)d_in[4];
  const float* dnbhf = (const float*)d_in[5];
  const float* dnWib = (const float*)d_in[6];
  const float* dnWhb = (const float*)d_in[7];
  const float* dnbib = (const float*)d_in[8];
  const float* dnbhb = (const float*)d_in[9];
  const float* W_e   = (const float*)d_in[10];
  const float* W_l   = (const float*)d_in[11];
  const float* W_w   = (const float*)d_in[12];
  const float* Wg    = (const float*)d_in[13];
  const float* bg    = (const float*)d_in[14];
  const float* dWif  = (const float*)d_in[15];
  const float* dWhf  = (const float*)d_in[16];
  const float* dbif  = (const float*)d_in[17];
  const float* dbhf  = (const float*)d_in[18];
  const float* dWib  = (const float*)d_in[19];
  const float* dWhb  = (const float*)d_in[20];
  const float* dbib  = (const float*)d_in[21];
  const float* dbhb  = (const float*)d_in[22];
  const float* Wc    = (const float*)d_in[23];
  const float* bc    = (const float*)d_in[24];
  const float* Wa1   = (const float*)d_in[25];
  const float* ba1   = (const float*)d_in[26];
  const float* Wa2   = (const float*)d_in[27];
  const float* ba2   = (const float*)d_in[28];
  const int* ents = (const int*)d_in[32];
  const int* locs = (const int*)d_in[33];
  const int* wrl  = (const int*)d_in[34];
  const int* cmds = (const int*)d_in[35];

  char* ws = (char*)d_ws;
  size_t off = 0;
#define WSP(name, type, count) type* name = (type*)(ws + off); off += (((size_t)(count))*sizeof(type) + 255) & ~(size_t)255;
  WSP(pT,     float, 20000*768);     // vocab table (reused per dir)
  WSP(pWprjT, float, 320*512);
  WSP(pCf,    float, 768*320);
  WSP(pCb,    float, 768*320);
  WSP(pWhFhi, __bf16, 768*256);
  WSP(pWhFlo, __bf16, 768*256);
  WSP(pWhBhi, __bf16, 768*256);
  WSP(pWhBlo, __bf16, 768*256);
  WSP(pWeT,   float, 512*512);
  WSP(pWlT,   float, 512*512);
  WSP(pWwT,   float, 512*512);
  WSP(pdWhF,  __bf16, 1536*512);
  WSP(pdWhB,  __bf16, 1536*512);
  WSP(pSeqh,  float, 11264*512);
  WSP(pWsum,  float, 1024*512);
  WSP(pRs,    float, 1024);
  WSP(pE1,    float, 1024*512);
  WSP(pE2,    float, 1024*512);
  WSP(pE3,    float, 1024*512);
  WSP(pY,     float, 1024*512);
  WSP(pGe,    float, 1024*512);
  WSP(pXf,    __bf16, 1024*1536);
  WSP(pXb,    __bf16, 1024*1536);
  WSP(pHA,    float, 32*512);
  WSP(pHB,    float, 32*512);
  WSP(pAmat,  float, 1024*1024);
  WSP(pGmat,  float, 1024*1024);
  WSP(pScf,   float, 1024);
  WSP(pBar,   unsigned, 64);
#undef WSP

  // 1. prep: transposes (f32), W_hh split planes, diff W bf16
  TTs tt;
  tt.t[0] = { W_prj, pWprjT, 512, 300, 320 };
  tt.t[1] = { W_e,   pWeT,   512, 512, 512 };
  tt.t[2] = { W_l,   pWlT,   512, 512, 512 };
  tt.t[3] = { W_w,   pWwT,   512, 512, 512 };
  k_prep_t<<<dim3(256,4), 256, 0, stream>>>(tt);
  PLs pl;
  pl.t[0] = { dnWhf, pWhFhi, pWhFlo, (size_t)768*256 };
  pl.t[1] = { dnWhb, pWhBhi, pWhBlo, (size_t)768*256 };
  k_prep_planes<<<dim3(256,2), 256, 0, stream>>>(pl);
  BCs bcs;
  bcs.t[0] = { dWhf, pdWhF, (size_t)1536*512 };
  bcs.t[1] = { dWhb, pdWhB, (size_t)1536*512 };
  k_prep_b16<<<dim3(512,2), 256, 0, stream>>>(bcs);

  // 2. fold Cf[n'][e] = sum_h Wif[n'][h] * W_prj[h][e]  (Cf cols 300..319 = 0 via pad)
  launch_gemm(stream, dnWif, pWprjT, nullptr, pCf, 768, 320, 512, 512, 512, 512, 0, 0);
  launch_gemm(stream, dnWib, pWprjT, nullptr, pCb, 768, 320, 512, 512, 512, 512, 0, 0);
  // 3+4. per-dir: vocab table (f32) then dn BiGRU
  launch_gemm(stream, emb, pCf, dnbif, pT, 20000, 768, 320, 300, 300, 320, 1, 0);
  dn_gru<<<352, 512, 0, stream>>>(pT, pWhFhi, pWhFlo, dnbhf, ents, locs, wrl, cmds, pSeqh, 0);
  launch_gemm(stream, emb, pCb, dnbib, pT, 20000, 768, 320, 300, 300, 320, 1, 0);
  dn_gru<<<352, 512, 0, stream>>>(pT, pWhBhi, pWhBlo, dnbhb, ents, locs, wrl, cmds, pSeqh, 1);
  // 5. graph encoding
  k_wsum<<<1024, 256, 0, stream>>>(pSeqh, pWsum);
  k_rowsum<<<1024, 64, 0, stream>>>(pSeqh, pRs);
  launch_gemm(stream, pSeqh,                   pWeT, nullptr, pE1, 1024, 512, 512, 512, 512, 512, 0, 0);
  launch_gemm(stream, pSeqh + (size_t)1024*512,pWlT, nullptr, pE2, 1024, 512, 512, 512, 512, 512, 0, 0);
  launch_gemm(stream, pWsum,                   pWwT, nullptr, pE3, 1024, 512, 512, 512, 512, 512, 0, 0);
  k_combine<<<2048, 256, 0, stream>>>(pE1, pE2, pE3, pRs, pY);
  launch_gemm(stream, pY, Wg, bg, pGe, 1024, 512, 512, 512, 512, 512, 2, 0);
  // 6. diff GRU input transforms (bf16 out)
  launch_gemm(stream, pGe, dWif, dbif, pXf, 1024, 1536, 512, 512, 512, 512, 1, 1);
  launch_gemm(stream, pGe, dWib, dbib, pXb, 1024, 1536, 512, 512, 512, 512, 1, 1);
  // 7. scoring
  launch_gemm(stream, pSeqh + (size_t)10240*512, Wa1, nullptr, pAmat, 1024, 1024, 512, 512, 512, 1024, 0, 0);
  launch_gemm(stream, pGe, Wa1 + 512, ba1, pGmat, 1024, 1024, 512, 512, 512, 1024, 1, 0);
  k_score<<<1024, 256, 0, stream>>>(pAmat, pGmat, Wa2, ba2, pScf);
  // 8. diff BiGRU: persistent kernel, 64 steps with device-scope barrier
  hipMemsetAsync(pHA, 0, 32*512*sizeof(float), stream);
  hipMemsetAsync(pBar, 0, 64*sizeof(unsigned), stream);
  diff_all<<<16, 256, 0, stream>>>(pHA, pHB, pdWhF, pdWhB, dbhf, dbhb, pXf, pXb, pBar);
  // 9. outputs (final h is in pHA after 64 steps: odd t writes hA)
  k_final<<<16, 64, 0, stream>>>(pScf, cmds, pHA, Wc, bc, (float*)d_out);
}

// Round 6
// 4041.967 us; speedup vs baseline: 1.1181x; 1.1181x over previous
//
#include <hip/hip_runtime.h>
#include <stdint.h>

#define DEVFN __device__ __forceinline__

typedef __attribute__((ext_vector_type(4))) float fx4;
typedef __attribute__((ext_vector_type(8))) short sx8;
typedef __bf16 bf16x8 __attribute__((ext_vector_type(8)));

DEVFN float eluf(float x){ return x>0.f ? x : __expf(x)-1.f; }
DEVFN float sigm(float x){ return 1.f/(1.f+__expf(-x)); }
DEVFN float tanhf_(float x){ float cx=fminf(10.f,fmaxf(-10.f,x)); float e=__expf(-2.f*cx); return (1.f-e)/(1.f+e); }

DEVFN fx4 MFMA(sx8 a, sx8 b, fx4 c){
  return __builtin_amdgcn_mfma_f32_16x16x32_bf16(
      __builtin_bit_cast(bf16x8,a), __builtin_bit_cast(bf16x8,b), c, 0,0,0);
}
DEVFN void splitf(float x, short& hi, short& lo){
  __bf16 h = (__bf16)x; hi = __builtin_bit_cast(short, h);
  __bf16 l = (__bf16)(x - (float)h); lo = __builtin_bit_cast(short, l);
}

// ---------------- prep kernels ----------------
struct TT { const float* src; float* dst; int srows, scols, drows; };
struct TTs { TT t[4]; };
__global__ void k_prep_t(TTs ts){   // dst[c][r] = src[r][c], zero-pad c>=scols
  TT tk = ts.t[blockIdx.y];
  size_t tot = (size_t)tk.drows * tk.srows;
  for (size_t i = (size_t)blockIdx.x*256 + threadIdx.x; i < tot; i += (size_t)gridDim.x*256){
    int c = (int)(i / tk.srows), r = (int)(i % tk.srows);
    tk.dst[i] = (c < tk.scols) ? tk.src[(size_t)r*tk.scols + c] : 0.f;
  }
}
struct PL { const float* src; __bf16* hi; __bf16* lo; size_t n; };
struct PLs { PL t[2]; };
__global__ void k_prep_planes(PLs ts){
  PL tk = ts.t[blockIdx.y];
  for (size_t i = (size_t)blockIdx.x*256 + threadIdx.x; i < tk.n; i += (size_t)gridDim.x*256){
    float x = tk.src[i];
    __bf16 h = (__bf16)x;
    tk.hi[i] = h; tk.lo[i] = (__bf16)(x - (float)h);
  }
}
struct BC { const float* src; __bf16* dst; size_t n; };
struct BCs { BC t[2]; };
__global__ void k_prep_b16(BCs ts){
  BC tk = ts.t[blockIdx.y];
  for (size_t i = (size_t)blockIdx.x*256 + threadIdx.x; i < tk.n; i += (size_t)gridDim.x*256)
    tk.dst[i] = (__bf16)tk.src[i];
}

// ------- split-precision GEMM: out[m][n] = sum_k A[m][k]*B[n][k], f32 in -------
// EPI: 0 none, 1 +bias, 2 +bias+elu ; OBF: 1 -> bf16 out, else f32
template<int EPI, int OBF>
__global__ __launch_bounds__(256) void gemm_k(
    const float* __restrict__ A, const float* __restrict__ B,
    const float* __restrict__ bias, void* __restrict__ out,
    int M, int N, int Kpad, int Kreal, int lda, int ldb)
{
  int bm = blockIdx.x*64, bn = blockIdx.y*64;
  int tid = threadIdx.x, l = tid&63, w = tid>>6;
  int wm = (w>>1)*32, wn = (w&1)*32;
  int lr = l&15, lk = l>>4;
  fx4 acc[2][2] = {};
  for (int k0 = 0; k0 < Kpad; k0 += 32) {
    sx8 ahi[2], alo[2], bhi[2], blo[2];
    bool full = (k0 + 32 <= Kreal);
    #pragma unroll
    for (int i=0;i<2;i++){
      int row = bm + wm + i*16 + lr; row = row < M ? row : M-1;
      int col = bn + wn + i*16 + lr;
      const float* ap = A + (size_t)row*lda + k0 + lk*8;
      const float* bp = B + (size_t)col*ldb + k0 + lk*8;
      float av[8], bv[8];
      if (full){
        *(fx4*)av = *(const fx4*)ap; *(fx4*)(av+4) = *(const fx4*)(ap+4);
        *(fx4*)bv = *(const fx4*)bp; *(fx4*)(bv+4) = *(const fx4*)(bp+4);
      } else {
        #pragma unroll
        for (int j=0;j<8;j++){
          int k = k0 + lk*8 + j;
          av[j] = (k < Kreal) ? ap[j] : 0.f;
          bv[j] = (k < Kreal) ? bp[j] : 0.f;
        }
      }
      #pragma unroll
      for (int j=0;j<8;j++){
        short h,lo2; splitf(av[j], h, lo2); ahi[i][j]=h; alo[i][j]=lo2;
        splitf(bv[j], h, lo2); bhi[i][j]=h; blo[i][j]=lo2;
      }
    }
    #pragma unroll
    for (int i=0;i<2;i++)
      #pragma unroll
      for (int j=0;j<2;j++){
        acc[i][j] = MFMA(alo[i], bhi[j], acc[i][j]);
        acc[i][j] = MFMA(ahi[i], blo[j], acc[i][j]);
        acc[i][j] = MFMA(ahi[i], bhi[j], acc[i][j]);
      }
  }
  #pragma unroll
  for (int i=0;i<2;i++)
    #pragma unroll
    for (int j=0;j<2;j++)
      #pragma unroll
      for (int q=0;q<4;q++){
        int m = bm + wm + i*16 + lk*4 + q;
        int n = bn + wn + j*16 + lr;
        if (m < M){
          float v = acc[i][j][q];
          if (EPI>=1) v += bias[n];
          if (EPI==2) v = eluf(v);
          if (OBF) ((__bf16*)out)[(size_t)m*N + n] = (__bf16)v;
          else     ((float*)out)[(size_t)m*N + n] = v;
        }
      }
}

// -------- dn BiGRU: 176 WGs x 64 chains, 512 thr (8 waves), split precision --------
// T reads nontemporal (evict-first) so they don't wipe W_hh (hi/lo, 1.57 MB) from L2.
__global__ __launch_bounds__(512,2) void dn_gru(
  const float* __restrict__ T,                 // [20000][768] f32
  const __bf16* __restrict__ Whi, const __bf16* __restrict__ Wlo,  // [768][256]
  const float* __restrict__ bh,
  const int* __restrict__ ents, const int* __restrict__ locs,
  const int* __restrict__ wrl, const int* __restrict__ cmd,
  float* __restrict__ seqh, int dir)
{
  __shared__ __align__(16) __bf16 hhi[64*256];  // swizzled: (m,k)-> m*256 + ((k>>3 ^ (m&31))<<3 | (k&7))
  __shared__ __align__(16) __bf16 hlo[64*256];
  __shared__ int toks[64];
  int wg = blockIdx.x;
  int cb = wg*64;
  int tid = threadIdx.x, l = tid&63, wn = tid>>6;   // 8 waves; wave wn owns j in [wn*32, wn*32+32)
  int lr = l&15, lk = l>>4;
  float bR[2], bZ[2], bN[2];
  #pragma unroll
  for (int jb=0;jb<2;jb++){
    int j = wn*32 + jb*16 + lr;
    bR[jb]=bh[j]; bZ[jb]=bh[256+j]; bN[jb]=bh[512+j];
  }
  for (int i=tid;i<64*256;i+=512){ hhi[i]=(__bf16)0.f; hlo[i]=(__bf16)0.f; }
  for (int s=0;s<16;s++){
    __syncthreads();
    if (tid<64){
      int c = cb+tid; const int* tp;
      if (c<1024) tp = ents + c*16;
      else if (c<2048) tp = locs + (c-1024)*16;
      else if (c<10240) tp = wrl + (c-2048)*16;
      else tp = cmd + (c-10240)*16;
      toks[tid] = tp[dir? 15-s : s];
    }
    __syncthreads();
    fx4 acc[4][6] = {};
    for (int kk=0;kk<8;kk++){
      sx8 ah[4], al[4];
      #pragma unroll
      for (int mt=0;mt<4;mt++){
        int row = mt*16 + lr;
        int c = (kk*4+lk) ^ (row&31);
        ah[mt] = *(const sx8*)&hhi[row*256 + c*8];
        al[mt] = *(const sx8*)&hlo[row*256 + c*8];
      }
      #pragma unroll
      for (int jb=0;jb<2;jb++)
        #pragma unroll
        for (int role=0;role<3;role++){
          int col = role*256 + wn*32 + jb*16 + lr;
          sx8 bh_ = *(const sx8*)(Whi + (size_t)col*256 + kk*32 + lk*8);
          sx8 bl_ = *(const sx8*)(Wlo + (size_t)col*256 + kk*32 + lk*8);
          #pragma unroll
          for (int mt=0;mt<4;mt++){
            fx4 a = acc[mt][jb*3+role];
            a = MFMA(al[mt], bh_, a);
            a = MFMA(ah[mt], bl_, a);
            a = MFMA(ah[mt], bh_, a);
            acc[mt][jb*3+role] = a;
          }
        }
    }
    float hnew[4][4][2];
    #pragma unroll
    for (int mt=0;mt<4;mt++){
      #pragma unroll
      for (int q=0;q<4;q++){
        int m = mt*16 + lk*4 + q;
        const float* trow = T + (size_t)toks[m]*768;
        #pragma unroll
        for (int jb=0;jb<2;jb++){
          int j = wn*32 + jb*16 + lr;
          float hr = acc[mt][jb*3+0][q] + bR[jb];
          float hz = acc[mt][jb*3+1][q] + bZ[jb];
          float hn = acc[mt][jb*3+2][q] + bN[jb];
          float xr = __builtin_nontemporal_load(trow + j);
          float xz = __builtin_nontemporal_load(trow + 256 + j);
          float xn = __builtin_nontemporal_load(trow + 512 + j);
          int cc = ((j>>3) ^ (m&31));
          int hidx = m*256 + cc*8 + (j&7);
          float ho = (float)hhi[hidx] + (float)hlo[hidx];
          float r = sigm(xr+hr), z = sigm(xz+hz);
          float n = tanhf_(xn + r*hn);
          hnew[mt][q][jb] = (1.f-z)*n + z*ho;
        }
      }
    }
    if (s < 15){
      __syncthreads();
      #pragma unroll
      for (int mt=0;mt<4;mt++)
        #pragma unroll
        for (int q=0;q<4;q++)
          #pragma unroll
          for (int jb=0;jb<2;jb++){
            int m = mt*16 + lk*4 + q;
            int j = wn*32 + jb*16 + lr;
            int cc = ((j>>3) ^ (m&31));
            int hidx = m*256 + cc*8 + (j&7);
            float v = hnew[mt][q][jb];
            __bf16 h = (__bf16)v;
            hhi[hidx] = h; hlo[hidx] = (__bf16)(v - (float)h);
          }
    } else {
      #pragma unroll
      for (int mt=0;mt<4;mt++)
        #pragma unroll
        for (int q=0;q<4;q++)
          #pragma unroll
          for (int jb=0;jb<2;jb++){
            int m = mt*16 + lk*4 + q;
            int j = wn*32 + jb*16 + lr;
            __builtin_nontemporal_store(hnew[mt][q][jb], &seqh[(size_t)(cb+m)*512 + dir*256 + j]);
          }
    }
  }
}

// ---------------- worlds sum / rowsum / combine (f32) ----------------
__global__ void k_wsum(const float* __restrict__ seqh, float* __restrict__ ws){
  int r = blockIdx.x;
  for (int c = threadIdx.x; c < 512; c += 256){
    float a = 0.f;
    #pragma unroll
    for (int w8=0; w8<8; w8++) a += seqh[((size_t)2048 + r*8 + w8)*512 + c];
    ws[(size_t)r*512 + c] = a;
  }
}
__global__ void k_rowsum(const float* __restrict__ seqh, float* __restrict__ rs){
  int r = blockIdx.x, l = threadIdx.x;  // 64 threads
  float a = 0.f;
  for (int c=l;c<512;c+=64) a += seqh[(size_t)r*512+c];
  #pragma unroll
  for (int o=32;o>0;o>>=1) a += __shfl_down(a,o);
  if (l==0) rs[r]=a;
}
__global__ void k_combine(const float* __restrict__ E1, const float* __restrict__ E2,
                          const float* __restrict__ E3, const float* __restrict__ rs,
                          float* __restrict__ y){
  size_t i = (size_t)blockIdx.x*256 + threadIdx.x;  // grid 2048 -> 524288 exact
  int r = (int)(i >> 9);
  float g = eluf(E1[i] + rs[r]) + eluf(E2[i]) + E3[i];
  y[i] = eluf(g);
}

// ------- diff GRU step (both dirs), H=512, batch 16; h f32, A-split (2 MFMA) -------
__global__ __launch_bounds__(256) void diff_step(
  const float* __restrict__ hsrc, float* __restrict__ hdst,
  const __bf16* __restrict__ Whf, const __bf16* __restrict__ Whb,
  const float* __restrict__ bhf, const float* __restrict__ bhb,
  const __bf16* __restrict__ Xf, const __bf16* __restrict__ Xb, int t)
{
  int wg = blockIdx.x;           // 16: dir*8 + seg
  int dir = wg>>3, seg = wg&7;
  const __bf16* W = dir? Whb: Whf;
  const float* bh = dir? bhb: bhf;
  const __bf16* X = dir? Xb: Xf;
  int tt = dir? 63-t : t;
  int tid = threadIdx.x, l = tid&63, w = tid>>6;
  int lr=l&15, lk=l>>4;
  int jbase = seg*64 + w*16;
  fx4 acc[3] = {};
  const float* hrow = hsrc + (size_t)dir*16*512;
  for (int kk=0;kk<16;kk++){
    const float* ap = hrow + (size_t)lr*512 + kk*32 + lk*8;
    float av[8];
    *(fx4*)av = *(const fx4*)ap; *(fx4*)(av+4) = *(const fx4*)(ap+4);
    sx8 ah, al;
    #pragma unroll
    for (int j=0;j<8;j++){ short h,lo; splitf(av[j],h,lo); ah[j]=h; al[j]=lo; }
    #pragma unroll
    for (int role=0;role<3;role++){
      int col = role*512 + jbase + lr;
      sx8 b = *(const sx8*)(W + (size_t)col*512 + kk*32 + lk*8);
      acc[role] = MFMA(al, b, acc[role]);
      acc[role] = MFMA(ah, b, acc[role]);
    }
  }
  #pragma unroll
  for (int q=0;q<4;q++){
    int m = lk*4+q;
    int j = jbase + lr;
    float hr = acc[0][q] + bh[j];
    float hz = acc[1][q] + bh[512+j];
    float hn = acc[2][q] + bh[1024+j];
    const __bf16* xrow = X + ((size_t)m*64 + tt)*1536;
    float xr = (float)xrow[j], xz = (float)xrow[512+j], xn = (float)xrow[1024+j];
    float ho = hrow[(size_t)m*512 + j];
    float r = sigm(xr+hr), z = sigm(xz+hz);
    float n = tanhf_(xn + r*hn);
    hdst[((size_t)dir*16 + m)*512 + j] = (1.f-z)*n + z*ho;
  }
}

// ---------------- scoring ----------------
__global__ __launch_bounds__(256) void k_score(
  const float* __restrict__ Amat, const float* __restrict__ Gmat,
  const float* __restrict__ Wa2, const float* __restrict__ ba2, float* __restrict__ sc)
{
  __shared__ float red[4];
  int p = blockIdx.x, b = p>>6, tid = threadIdx.x;
  float av[4], wv[4];
  #pragma unroll
  for (int k=0;k<4;k++){ av[k] = Amat[(size_t)p*1024 + tid + k*256]; wv[k] = Wa2[tid + k*256]; }
  float acc = 0.f;
  for (int n=0;n<64;n++){
    const float* g = Gmat + ((size_t)b*64+n)*1024;
    #pragma unroll
    for (int k=0;k<4;k++) acc += wv[k]*eluf(av[k] + g[tid + k*256]);
  }
  #pragma unroll
  for (int o=32;o>0;o>>=1) acc += __shfl_down(acc,o);
  if ((tid&63)==0) red[tid>>6] = acc;
  __syncthreads();
  if (tid==0) sc[p] = (red[0]+red[1]+red[2]+red[3])*(1.f/64.f) + ba2[0];
}

__global__ void k_final(const float* __restrict__ sc, const int* __restrict__ cmds,
                        const float* __restrict__ hfin, const float* __restrict__ Wc,
                        const float* __restrict__ bc, float* __restrict__ out)
{
  int b = blockIdx.x, l = threadIdx.x;   // 64 threads
  out[b*64+l] = sc[b*64+l];
  int ssum = 0;
  const int* cr = cmds + (b*64+l)*16;
  #pragma unroll
  for (int k=0;k<16;k++) ssum += cr[k];
  float v = ssum>0 ? sc[b*64+l] : -1e9f;
  int idx = l;
  #pragma unroll
  for (int o=32;o>0;o>>=1){
    float ov = __shfl_down(v,o); int oi = __shfl_down(idx,o);
    if (ov > v || (ov==v && oi<idx)) { v=ov; idx=oi; }
  }
  if (l==0) out[1024 + b] = (float)idx;
  float a = 0.f;
  for (int j=l;j<512;j+=64) a += hfin[(size_t)b*512+j] * Wc[j];
  for (int j=l;j<512;j+=64) a += hfin[(size_t)(16+b)*512+j] * Wc[512+j];
  #pragma unroll
  for (int o=32;o>0;o>>=1) a += __shfl_down(a,o);
  if (l==0) out[1040 + b] = a + bc[0];
}

// ---------------- host ----------------
static inline void launch_gemm(hipStream_t st, const float* A, const float* B,
                               const float* bias, void* out, int M, int N,
                               int Kpad, int Kreal, int lda, int ldb, int epi, int obf)
{
  dim3 g((M+63)/64, N/64), blk(256);
  if      (epi==0 && obf==0) gemm_k<0,0><<<g,blk,0,st>>>(A,B,bias,out,M,N,Kpad,Kreal,lda,ldb);
  else if (epi==1 && obf==0) gemm_k<1,0><<<g,blk,0,st>>>(A,B,bias,out,M,N,Kpad,Kreal,lda,ldb);
  else if (epi==2 && obf==0) gemm_k<2,0><<<g,blk,0,st>>>(A,B,bias,out,M,N,Kpad,Kreal,lda,ldb);
  else                       gemm_k<1,1><<<g,blk,0,st>>>(A,B,bias,out,M,N,Kpad,Kreal,lda,ldb);
}

extern "C" void kernel_launch(void* const* d_in, const int* in_sizes, int n_in,
                              void* d_out, int out_size, void* d_ws, size_t ws_size,
                              hipStream_t stream) {
  (void)in_sizes; (void)n_in; (void)out_size; (void)ws_size;
  const float* emb   = (const float*)d_in[0];
  const float* W_prj = (const float*)d_in[1];
  const float* dnWif = (const float*)d_in[2];
  const float* dnWhf = (const float*)d_in[3];
  const float* dnbif = (const float*)d_in[4];
  const float* dnbhf = (const float*)d_in[5];
  const float* dnWib = (const float*)d_in[6];
  const float* dnWhb = (const float*)d_in[7];
  const float* dnbib = (const float*)d_in[8];
  const float* dnbhb = (const float*)d_in[9];
  const float* W_e   = (const float*)d_in[10];
  const float* W_l   = (const float*)d_in[11];
  const float* W_w   = (const float*)d_in[12];
  const float* Wg    = (const float*)d_in[13];
  const float* bg    = (const float*)d_in[14];
  const float* dWif  = (const float*)d_in[15];
  const float* dWhf  = (const float*)d_in[16];
  const float* dbif  = (const float*)d_in[17];
  const float* dbhf  = (const float*)d_in[18];
  const float* dWib  = (const float*)d_in[19];
  const float* dWhb  = (const float*)d_in[20];
  const float* dbib  = (const float*)d_in[21];
  const float* dbhb  = (const float*)d_in[22];
  const float* Wc    = (const float*)d_in[23];
  const float* bc    = (const float*)d_in[24];
  const float* Wa1   = (const float*)d_in[25];
  const float* ba1   = (const float*)d_in[26];
  const float* Wa2   = (const float*)d_in[27];
  const float* ba2   = (const float*)d_in[28];
  const int* ents = (const int*)d_in[32];
  const int* locs = (const int*)d_in[33];
  const int* wrl  = (const int*)d_in[34];
  const int* cmds = (const int*)d_in[35];

  char* ws = (char*)d_ws;
  size_t off = 0;
#define WSP(name, type, count) type* name = (type*)(ws + off); off += (((size_t)(count))*sizeof(type) + 255) & ~(size_t)255;
  WSP(pT,     float, 20000*768);     // vocab table f32 (reused per dir)
  WSP(pWprjT, float, 320*512);
  WSP(pCf,    float, 768*320);
  WSP(pCb,    float, 768*320);
  WSP(pWhFhi, __bf16, 768*256);
  WSP(pWhFlo, __bf16, 768*256);
  WSP(pWhBhi, __bf16, 768*256);
  WSP(pWhBlo, __bf16, 768*256);
  WSP(pWeT,   float, 512*512);
  WSP(pWlT,   float, 512*512);
  WSP(pWwT,   float, 512*512);
  WSP(pdWhF,  __bf16, 1536*512);
  WSP(pdWhB,  __bf16, 1536*512);
  WSP(pSeqh,  float, 11264*512);
  WSP(pWsum,  float, 1024*512);
  WSP(pRs,    float, 1024);
  WSP(pE1,    float, 1024*512);
  WSP(pE2,    float, 1024*512);
  WSP(pE3,    float, 1024*512);
  WSP(pY,     float, 1024*512);
  WSP(pGe,    float, 1024*512);
  WSP(pXf,    __bf16, 1024*1536);
  WSP(pXb,    __bf16, 1024*1536);
  WSP(pHA,    float, 32*512);
  WSP(pHB,    float, 32*512);
  WSP(pAmat,  float, 1024*1024);
  WSP(pGmat,  float, 1024*1024);
  WSP(pScf,   float, 1024);
#undef WSP

  // 1. prep: transposes (f32), W_hh split planes, diff W bf16
  TTs tt;
  tt.t[0] = { W_prj, pWprjT, 512, 300, 320 };
  tt.t[1] = { W_e,   pWeT,   512, 512, 512 };
  tt.t[2] = { W_l,   pWlT,   512, 512, 512 };
  tt.t[3] = { W_w,   pWwT,   512, 512, 512 };
  k_prep_t<<<dim3(256,4), 256, 0, stream>>>(tt);
  PLs pl;
  pl.t[0] = { dnWhf, pWhFhi, pWhFlo, (size_t)768*256 };
  pl.t[1] = { dnWhb, pWhBhi, pWhBlo, (size_t)768*256 };
  k_prep_planes<<<dim3(256,2), 256, 0, stream>>>(pl);
  BCs bcs;
  bcs.t[0] = { dWhf, pdWhF, (size_t)1536*512 };
  bcs.t[1] = { dWhb, pdWhB, (size_t)1536*512 };
  k_prep_b16<<<dim3(512,2), 256, 0, stream>>>(bcs);

  // 2. fold Cf[n'][e] = sum_h Wif[n'][h] * W_prj[h][e]  (Cf cols 300..319 = 0 via pad)
  launch_gemm(stream, dnWif, pWprjT, nullptr, pCf, 768, 320, 512, 512, 512, 512, 0, 0);
  launch_gemm(stream, dnWib, pWprjT, nullptr, pCb, 768, 320, 512, 512, 512, 512, 0, 0);
  // 3+4. per-dir: vocab table (f32) then dn BiGRU
  launch_gemm(stream, emb, pCf, dnbif, pT, 20000, 768, 320, 300, 300, 320, 1, 0);
  dn_gru<<<176, 512, 0, stream>>>(pT, pWhFhi, pWhFlo, dnbhf, ents, locs, wrl, cmds, pSeqh, 0);
  launch_gemm(stream, emb, pCb, dnbib, pT, 20000, 768, 320, 300, 300, 320, 1, 0);
  dn_gru<<<176, 512, 0, stream>>>(pT, pWhBhi, pWhBlo, dnbhb, ents, locs, wrl, cmds, pSeqh, 1);
  // 5. graph encoding
  k_wsum<<<1024, 256, 0, stream>>>(pSeqh, pWsum);
  k_rowsum<<<1024, 64, 0, stream>>>(pSeqh, pRs);
  launch_gemm(stream, pSeqh,                   pWeT, nullptr, pE1, 1024, 512, 512, 512, 512, 512, 0, 0);
  launch_gemm(stream, pSeqh + (size_t)1024*512,pWlT, nullptr, pE2, 1024, 512, 512, 512, 512, 512, 0, 0);
  launch_gemm(stream, pWsum,                   pWwT, nullptr, pE3, 1024, 512, 512, 512, 512, 512, 0, 0);
  k_combine<<<2048, 256, 0, stream>>>(pE1, pE2, pE3, pRs, pY);
  launch_gemm(stream, pY, Wg, bg, pGe, 1024, 512, 512, 512, 512, 512, 2, 0);
  // 6. diff GRU input transforms (bf16 out)
  launch_gemm(stream, pGe, dWif, dbif, pXf, 1024, 1536, 512, 512, 512, 512, 1, 1);
  launch_gemm(stream, pGe, dWib, dbib, pXb, 1024, 1536, 512, 512, 512, 512, 1, 1);
  // 7. scoring
  launch_gemm(stream, pSeqh + (size_t)10240*512, Wa1, nullptr, pAmat, 1024, 1024, 512, 512, 512, 1024, 0, 0);
  launch_gemm(stream, pGe, Wa1 + 512, ba1, pGmat, 1024, 1024, 512, 512, 512, 1024, 1, 0);
  k_score<<<1024, 256, 0, stream>>>(pAmat, pGmat, Wa2, ba2, pScf);
  // 8. diff BiGRU: 64 serial micro-launches (graph replay makes these cheap)
  hipMemsetAsync(pHA, 0, 32*512*sizeof(float), stream);
  float* ha = pHA; float* hb = pHB;
  for (int t=0; t<64; ++t){
    diff_step<<<16, 256, 0, stream>>>(ha, hb, pdWhF, pdWhB, dbhf, dbhb, pXf, pXb, t);
    float* tmp = ha; ha = hb; hb = tmp;
  }
  // 9. outputs
  k_final<<<16, 64, 0, stream>>>(pScf, cmds, ha, Wc, bc, (float*)d_out);
}

// Round 7
// 2858.554 us; speedup vs baseline: 1.5810x; 1.4140x over previous
//
#include <hip/hip_runtime.h>
#include <stdint.h>

#define DEVFN __device__ __forceinline__

typedef __attribute__((ext_vector_type(4))) float fx4;
typedef __attribute__((ext_vector_type(8))) short sx8;
typedef __bf16 bf16x8 __attribute__((ext_vector_type(8)));

DEVFN float eluf(float x){ return x>0.f ? x : __expf(x)-1.f; }
DEVFN float sigm(float x){ return 1.f/(1.f+__expf(-x)); }
DEVFN float tanhf_(float x){ float cx=fminf(10.f,fmaxf(-10.f,x)); float e=__expf(-2.f*cx); return (1.f-e)/(1.f+e); }

DEVFN fx4 MFMA(sx8 a, sx8 b, fx4 c){
  return __builtin_amdgcn_mfma_f32_16x16x32_bf16(
      __builtin_bit_cast(bf16x8,a), __builtin_bit_cast(bf16x8,b), c, 0,0,0);
}
DEVFN void splitf(float x, short& hi, short& lo){
  __bf16 h = (__bf16)x; hi = __builtin_bit_cast(short, h);
  __bf16 l = (__bf16)(x - (float)h); lo = __builtin_bit_cast(short, l);
}

// ---------------- prep kernels ----------------
struct TT { const float* src; float* dst; int srows, scols, drows; };
struct TTs { TT t[4]; };
__global__ void k_prep_t(TTs ts){   // dst[c][r] = src[r][c], zero-pad c>=scols
  TT tk = ts.t[blockIdx.y];
  size_t tot = (size_t)tk.drows * tk.srows;
  for (size_t i = (size_t)blockIdx.x*256 + threadIdx.x; i < tot; i += (size_t)gridDim.x*256){
    int c = (int)(i / tk.srows), r = (int)(i % tk.srows);
    tk.dst[i] = (c < tk.scols) ? tk.src[(size_t)r*tk.scols + c] : 0.f;
  }
}
struct PL { const float* src; __bf16* hi; __bf16* lo; size_t n; };
struct PLs { PL t[2]; };
__global__ void k_prep_planes(PLs ts){
  PL tk = ts.t[blockIdx.y];
  for (size_t i = (size_t)blockIdx.x*256 + threadIdx.x; i < tk.n; i += (size_t)gridDim.x*256){
    float x = tk.src[i];
    __bf16 h = (__bf16)x;
    tk.hi[i] = h; tk.lo[i] = (__bf16)(x - (float)h);
  }
}
struct BC { const float* src; __bf16* dst; size_t n; };
struct BCs { BC t[2]; };
__global__ void k_prep_b16(BCs ts){
  BC tk = ts.t[blockIdx.y];
  for (size_t i = (size_t)blockIdx.x*256 + threadIdx.x; i < tk.n; i += (size_t)gridDim.x*256)
    tk.dst[i] = (__bf16)tk.src[i];
}
// token table: [2][16][11264]
__global__ void k_toks(const int* __restrict__ ents, const int* __restrict__ locs,
                       const int* __restrict__ wrl, const int* __restrict__ cmd,
                       int* __restrict__ toks){
  int idx = blockIdx.x*256 + threadIdx.x;
  if (idx >= 2*16*11264) return;
  int dir = idx / (16*11264);
  int rem = idx % (16*11264);
  int s = rem / 11264, c = rem % 11264;
  const int* tp;
  if (c<1024) tp = ents + c*16;
  else if (c<2048) tp = locs + (c-1024)*16;
  else if (c<10240) tp = wrl + (c-2048)*16;
  else tp = cmd + (c-10240)*16;
  toks[idx] = tp[dir ? 15-s : s];
}

// ------- split-precision GEMM: out[m][n] = sum_k A[m][k]*B[n][k], f32 in -------
// EPI: 0 none, 1 +bias, 2 +bias+elu ; OBF: 1 -> bf16 out, else f32
template<int EPI, int OBF>
__global__ __launch_bounds__(256) void gemm_k(
    const float* __restrict__ A, const float* __restrict__ B,
    const float* __restrict__ bias, void* __restrict__ out,
    int M, int N, int Kpad, int Kreal, int lda, int ldb)
{
  int bm = blockIdx.x*64, bn = blockIdx.y*64;
  int tid = threadIdx.x, l = tid&63, w = tid>>6;
  int wm = (w>>1)*32, wn = (w&1)*32;
  int lr = l&15, lk = l>>4;
  fx4 acc[2][2] = {};
  for (int k0 = 0; k0 < Kpad; k0 += 32) {
    sx8 ahi[2], alo[2], bhi[2], blo[2];
    bool full = (k0 + 32 <= Kreal);
    #pragma unroll
    for (int i=0;i<2;i++){
      int row = bm + wm + i*16 + lr; row = row < M ? row : M-1;
      int col = bn + wn + i*16 + lr;
      const float* ap = A + (size_t)row*lda + k0 + lk*8;
      const float* bp = B + (size_t)col*ldb + k0 + lk*8;
      float av[8], bv[8];
      if (full){
        *(fx4*)av = *(const fx4*)ap; *(fx4*)(av+4) = *(const fx4*)(ap+4);
        *(fx4*)bv = *(const fx4*)bp; *(fx4*)(bv+4) = *(const fx4*)(bp+4);
      } else {
        #pragma unroll
        for (int j=0;j<8;j++){
          int k = k0 + lk*8 + j;
          av[j] = (k < Kreal) ? ap[j] : 0.f;
          bv[j] = (k < Kreal) ? bp[j] : 0.f;
        }
      }
      #pragma unroll
      for (int j=0;j<8;j++){
        short h,lo2; splitf(av[j], h, lo2); ahi[i][j]=h; alo[i][j]=lo2;
        splitf(bv[j], h, lo2); bhi[i][j]=h; blo[i][j]=lo2;
      }
    }
    #pragma unroll
    for (int i=0;i<2;i++)
      #pragma unroll
      for (int j=0;j<2;j++){
        acc[i][j] = MFMA(alo[i], bhi[j], acc[i][j]);
        acc[i][j] = MFMA(ahi[i], blo[j], acc[i][j]);
        acc[i][j] = MFMA(ahi[i], bhi[j], acc[i][j]);
      }
  }
  #pragma unroll
  for (int i=0;i<2;i++)
    #pragma unroll
    for (int j=0;j<2;j++)
      #pragma unroll
      for (int q=0;q<4;q++){
        int m = bm + wm + i*16 + lk*4 + q;
        int n = bn + wn + j*16 + lr;
        if (m < M){
          float v = acc[i][j][q];
          if (EPI>=1) v += bias[n];
          if (EPI==2) v = eluf(v);
          if (OBF) ((__bf16*)out)[(size_t)m*N + n] = (__bf16)v;
          else     ((float*)out)[(size_t)m*N + n] = v;
        }
      }
}

// -------- dn GRU step as batched GEMM: all 11264 chains of one dir --------
// H state pre-split hi/lo bf16 planes [11264][256]; W pre-split [768][256].
// grid (176, 4): 64 chains x 64 j-cols (x3 roles internally). s==0 skips GEMM.
__global__ __launch_bounds__(256) void dn_step(
  const __bf16* __restrict__ Hshi, const __bf16* __restrict__ Hslo,
  __bf16* __restrict__ Hdhi, __bf16* __restrict__ Hdlo,
  const __bf16* __restrict__ Whi, const __bf16* __restrict__ Wlo,
  const float* __restrict__ bias, const float* __restrict__ T,
  const int* __restrict__ toks,   // [16][11264] for this dir
  float* __restrict__ seqh, int s, int dir)
{
  int bm = blockIdx.x*64;
  int bj = blockIdx.y*64;
  int tid = threadIdx.x, l = tid&63, w = tid>>6;
  int wm = (w>>1)*32, wn = (w&1)*32;
  int lr = l&15, lk = l>>4;
  fx4 acc[2][2][3] = {};
  if (s > 0){
    for (int kk=0;kk<8;kk++){
      sx8 ah[2], al[2];
      #pragma unroll
      for (int i=0;i<2;i++){
        int m = bm + wm + i*16 + lr;
        ah[i] = *(const sx8*)(Hshi + (size_t)m*256 + kk*32 + lk*8);
        al[i] = *(const sx8*)(Hslo + (size_t)m*256 + kk*32 + lk*8);
      }
      #pragma unroll
      for (int jt=0;jt<2;jt++){
        #pragma unroll
        for (int role=0;role<3;role++){
          int col = role*256 + bj + wn + jt*16 + lr;
          sx8 bhf = *(const sx8*)(Whi + (size_t)col*256 + kk*32 + lk*8);
          sx8 blf = *(const sx8*)(Wlo + (size_t)col*256 + kk*32 + lk*8);
          #pragma unroll
          for (int i=0;i<2;i++){
            fx4 a = acc[i][jt][role];
            a = MFMA(al[i], bhf, a);
            a = MFMA(ah[i], blf, a);
            a = MFMA(ah[i], bhf, a);
            acc[i][jt][role] = a;
          }
        }
      }
    }
  }
  const int* tks = toks + s*11264;
  #pragma unroll
  for (int i=0;i<2;i++){
    #pragma unroll
    for (int q=0;q<4;q++){
      int m = bm + wm + i*16 + lk*4 + q;
      int tok = tks[m];
      const float* trow = T + (size_t)tok*768;
      #pragma unroll
      for (int jt=0;jt<2;jt++){
        int j = bj + wn + jt*16 + lr;
        float hr = acc[i][jt][0][q] + bias[j];
        float hz = acc[i][jt][1][q] + bias[256+j];
        float hn = acc[i][jt][2][q] + bias[512+j];
        float xr = trow[j], xz = trow[256+j], xn = trow[512+j];
        float ho = 0.f;
        if (s > 0) ho = (float)Hshi[(size_t)m*256+j] + (float)Hslo[(size_t)m*256+j];
        float r = sigm(xr+hr), z = sigm(xz+hz);
        float n = tanhf_(xn + r*hn);
        float v = (1.f-z)*n + z*ho;
        __bf16 hh = (__bf16)v;
        Hdhi[(size_t)m*256+j] = hh;
        Hdlo[(size_t)m*256+j] = (__bf16)(v - (float)hh);
        if (s == 15) seqh[(size_t)m*512 + dir*256 + j] = v;
      }
    }
  }
}

// ---------------- worlds sum / rowsum / combine (f32) ----------------
__global__ void k_wsum(const float* __restrict__ seqh, float* __restrict__ ws){
  int r = blockIdx.x;
  for (int c = threadIdx.x; c < 512; c += 256){
    float a = 0.f;
    #pragma unroll
    for (int w8=0; w8<8; w8++) a += seqh[((size_t)2048 + r*8 + w8)*512 + c];
    ws[(size_t)r*512 + c] = a;
  }
}
__global__ void k_rowsum(const float* __restrict__ seqh, float* __restrict__ rs){
  int r = blockIdx.x, l = threadIdx.x;  // 64 threads
  float a = 0.f;
  for (int c=l;c<512;c+=64) a += seqh[(size_t)r*512+c];
  #pragma unroll
  for (int o=32;o>0;o>>=1) a += __shfl_down(a,o);
  if (l==0) rs[r]=a;
}
__global__ void k_combine(const float* __restrict__ E1, const float* __restrict__ E2,
                          const float* __restrict__ E3, const float* __restrict__ rs,
                          float* __restrict__ y){
  size_t i = (size_t)blockIdx.x*256 + threadIdx.x;  // grid 2048 -> 524288 exact
  int r = (int)(i >> 9);
  float g = eluf(E1[i] + rs[r]) + eluf(E2[i]) + E3[i];
  y[i] = eluf(g);
}

// ------- diff GRU step (both dirs), H=512, batch 16; h f32, A-split (2 MFMA) -------
__global__ __launch_bounds__(256) void diff_step(
  const float* __restrict__ hsrc, float* __restrict__ hdst,
  const __bf16* __restrict__ Whf, const __bf16* __restrict__ Whb,
  const float* __restrict__ bhf, const float* __restrict__ bhb,
  const __bf16* __restrict__ Xf, const __bf16* __restrict__ Xb, int t)
{
  int wg = blockIdx.x;           // 16: dir*8 + seg
  int dir = wg>>3, seg = wg&7;
  const __bf16* W = dir? Whb: Whf;
  const float* bh = dir? bhb: bhf;
  const __bf16* X = dir? Xb: Xf;
  int tt = dir? 63-t : t;
  int tid = threadIdx.x, l = tid&63, w = tid>>6;
  int lr=l&15, lk=l>>4;
  int jbase = seg*64 + w*16;
  fx4 acc[3] = {};
  const float* hrow = hsrc + (size_t)dir*16*512;
  for (int kk=0;kk<16;kk++){
    const float* ap = hrow + (size_t)lr*512 + kk*32 + lk*8;
    float av[8];
    *(fx4*)av = *(const fx4*)ap; *(fx4*)(av+4) = *(const fx4*)(ap+4);
    sx8 ah, al;
    #pragma unroll
    for (int j=0;j<8;j++){ short h,lo; splitf(av[j],h,lo); ah[j]=h; al[j]=lo; }
    #pragma unroll
    for (int role=0;role<3;role++){
      int col = role*512 + jbase + lr;
      sx8 b = *(const sx8*)(W + (size_t)col*512 + kk*32 + lk*8);
      acc[role] = MFMA(al, b, acc[role]);
      acc[role] = MFMA(ah, b, acc[role]);
    }
  }
  #pragma unroll
  for (int q=0;q<4;q++){
    int m = lk*4+q;
    int j = jbase + lr;
    float hr = acc[0][q] + bh[j];
    float hz = acc[1][q] + bh[512+j];
    float hn = acc[2][q] + bh[1024+j];
    const __bf16* xrow = X + ((size_t)m*64 + tt)*1536;
    float xr = (float)xrow[j], xz = (float)xrow[512+j], xn = (float)xrow[1024+j];
    float ho = hrow[(size_t)m*512 + j];
    float r = sigm(xr+hr), z = sigm(xz+hz);
    float n = tanhf_(xn + r*hn);
    hdst[((size_t)dir*16 + m)*512 + j] = (1.f-z)*n + z*ho;
  }
}

// ---------------- scoring ----------------
__global__ __launch_bounds__(256) void k_score(
  const float* __restrict__ Amat, const float* __restrict__ Gmat,
  const float* __restrict__ Wa2, const float* __restrict__ ba2, float* __restrict__ sc)
{
  __shared__ float red[4];
  int p = blockIdx.x, b = p>>6, tid = threadIdx.x;
  float av[4], wv[4];
  #pragma unroll
  for (int k=0;k<4;k++){ av[k] = Amat[(size_t)p*1024 + tid + k*256]; wv[k] = Wa2[tid + k*256]; }
  float acc = 0.f;
  for (int n=0;n<64;n++){
    const float* g = Gmat + ((size_t)b*64+n)*1024;
    #pragma unroll
    for (int k=0;k<4;k++) acc += wv[k]*eluf(av[k] + g[tid + k*256]);
  }
  #pragma unroll
  for (int o=32;o>0;o>>=1) acc += __shfl_down(acc,o);
  if ((tid&63)==0) red[tid>>6] = acc;
  __syncthreads();
  if (tid==0) sc[p] = (red[0]+red[1]+red[2]+red[3])*(1.f/64.f) + ba2[0];
}

__global__ void k_final(const float* __restrict__ sc, const int* __restrict__ cmds,
                        const float* __restrict__ hfin, const float* __restrict__ Wc,
                        const float* __restrict__ bc, float* __restrict__ out)
{
  int b = blockIdx.x, l = threadIdx.x;   // 64 threads
  out[b*64+l] = sc[b*64+l];
  int ssum = 0;
  const int* cr = cmds + (b*64+l)*16;
  #pragma unroll
  for (int k=0;k<16;k++) ssum += cr[k];
  float v = ssum>0 ? sc[b*64+l] : -1e9f;
  int idx = l;
  #pragma unroll
  for (int o=32;o>0;o>>=1){
    float ov = __shfl_down(v,o); int oi = __shfl_down(idx,o);
    if (ov > v || (ov==v && oi<idx)) { v=ov; idx=oi; }
  }
  if (l==0) out[1024 + b] = (float)idx;
  float a = 0.f;
  for (int j=l;j<512;j+=64) a += hfin[(size_t)b*512+j] * Wc[j];
  for (int j=l;j<512;j+=64) a += hfin[(size_t)(16+b)*512+j] * Wc[512+j];
  #pragma unroll
  for (int o=32;o>0;o>>=1) a += __shfl_down(a,o);
  if (l==0) out[1040 + b] = a + bc[0];
}

// ---------------- host ----------------
static inline void launch_gemm(hipStream_t st, const float* A, const float* B,
                               const float* bias, void* out, int M, int N,
                               int Kpad, int Kreal, int lda, int ldb, int epi, int obf)
{
  dim3 g((M+63)/64, N/64), blk(256);
  if      (epi==0 && obf==0) gemm_k<0,0><<<g,blk,0,st>>>(A,B,bias,out,M,N,Kpad,Kreal,lda,ldb);
  else if (epi==1 && obf==0) gemm_k<1,0><<<g,blk,0,st>>>(A,B,bias,out,M,N,Kpad,Kreal,lda,ldb);
  else if (epi==2 && obf==0) gemm_k<2,0><<<g,blk,0,st>>>(A,B,bias,out,M,N,Kpad,Kreal,lda,ldb);
  else                       gemm_k<1,1><<<g,blk,0,st>>>(A,B,bias,out,M,N,Kpad,Kreal,lda,ldb);
}

extern "C" void kernel_launch(void* const* d_in, const int* in_sizes, int n_in,
                              void* d_out, int out_size, void* d_ws, size_t ws_size,
                              hipStream_t stream) {
  (void)in_sizes; (void)n_in; (void)out_size; (void)ws_size;
  const float* emb   = (const float*)d_in[0];
  const float* W_prj = (const float*)d_in[1];
  const float* dnWif = (const float*)d_in[2];
  const float* dnWhf = (const float*)d_in[3];
  const float* dnbif = (const float*)d_in[4];
  const float* dnbhf = (const float*)d_in[5];
  const float* dnWib = (const float*)d_in[6];
  const float* dnWhb = (const float*)d_in[7];
  const float* dnbib = (const float*)d_in[8];
  const float* dnbhb = (const float*)d_in[9];
  const float* W_e   = (const float*)d_in[10];
  const float* W_l   = (const float*)d_in[11];
  const float* W_w   = (const float*)d_in[12];
  const float* Wg    = (const float*)d_in[13];
  const float* bg    = (const float*)d_in[14];
  const float* dWif  = (const float*)d_in[15];
  const float* dWhf  = (const float*)d_in[16];
  const float* dbif  = (const float*)d_in[17];
  const float* dbhf  = (const float*)d_in[18];
  const float* dWib  = (const float*)d_in[19];
  const float* dWhb  = (const float*)d_in[20];
  const float* dbib  = (const float*)d_in[21];
  const float* dbhb  = (const float*)d_in[22];
  const float* Wc    = (const float*)d_in[23];
  const float* bc    = (const float*)d_in[24];
  const float* Wa1   = (const float*)d_in[25];
  const float* ba1   = (const float*)d_in[26];
  const float* Wa2   = (const float*)d_in[27];
  const float* ba2   = (const float*)d_in[28];
  const int* ents = (const int*)d_in[32];
  const int* locs = (const int*)d_in[33];
  const int* wrl  = (const int*)d_in[34];
  const int* cmds = (const int*)d_in[35];

  char* ws = (char*)d_ws;
  size_t off = 0;
#define WSP(name, type, count) type* name = (type*)(ws + off); off += (((size_t)(count))*sizeof(type) + 255) & ~(size_t)255;
  WSP(pT,     float, 20000*768);     // vocab table during dn; post-dn scratch union
  WSP(pWprjT, float, 320*512);
  WSP(pCf,    float, 768*320);
  WSP(pCb,    float, 768*320);
  WSP(pWhFhi, __bf16, 768*256);
  WSP(pWhFlo, __bf16, 768*256);
  WSP(pWhBhi, __bf16, 768*256);
  WSP(pWhBlo, __bf16, 768*256);
  WSP(pWeT,   float, 512*512);
  WSP(pWlT,   float, 512*512);
  WSP(pWwT,   float, 512*512);
  WSP(pdWhF,  __bf16, 1536*512);
  WSP(pdWhB,  __bf16, 1536*512);
  WSP(pSeqh,  float, 11264*512);
  WSP(pH0hi,  __bf16, 11264*256);
  WSP(pH0lo,  __bf16, 11264*256);
  WSP(pH1hi,  __bf16, 11264*256);
  WSP(pH1lo,  __bf16, 11264*256);
  WSP(pToks,  int,    2*16*11264);
  WSP(pHA,    float, 32*512);
  WSP(pHB,    float, 32*512);
  WSP(pRs,    float, 1024);
  WSP(pScf,   float, 1024);
#undef WSP
  // post-dn scratch lives inside pT (T is dead once both dn passes finish)
  const size_t SZ = (size_t)1024*512*4;           // 2 MB unit
  char* sc = (char*)pT;
  float* pWsum = (float*)(sc + 0*SZ);
  float* pE1   = (float*)(sc + 1*SZ);
  float* pE2   = (float*)(sc + 2*SZ);
  float* pE3   = (float*)(sc + 3*SZ);
  float* pY    = (float*)(sc + 4*SZ);
  float* pGe   = (float*)(sc + 5*SZ);
  float* pAmat = (float*)(sc + 6*SZ);              // 4 MB
  float* pGmat = (float*)(sc + 8*SZ);              // 4 MB
  __bf16* pXf  = (__bf16*)(sc + 10*SZ);            // 3 MB
  __bf16* pXb  = (__bf16*)(sc + 10*SZ + (size_t)1024*1536*2);

  // 1. prep: transposes (f32), W_hh split planes, diff W bf16, token table
  TTs tt;
  tt.t[0] = { W_prj, pWprjT, 512, 300, 320 };
  tt.t[1] = { W_e,   pWeT,   512, 512, 512 };
  tt.t[2] = { W_l,   pWlT,   512, 512, 512 };
  tt.t[3] = { W_w,   pWwT,   512, 512, 512 };
  k_prep_t<<<dim3(256,4), 256, 0, stream>>>(tt);
  PLs pl;
  pl.t[0] = { dnWhf, pWhFhi, pWhFlo, (size_t)768*256 };
  pl.t[1] = { dnWhb, pWhBhi, pWhBlo, (size_t)768*256 };
  k_prep_planes<<<dim3(256,2), 256, 0, stream>>>(pl);
  BCs bcs;
  bcs.t[0] = { dWhf, pdWhF, (size_t)1536*512 };
  bcs.t[1] = { dWhb, pdWhB, (size_t)1536*512 };
  k_prep_b16<<<dim3(512,2), 256, 0, stream>>>(bcs);
  k_toks<<<1408, 256, 0, stream>>>(ents, locs, wrl, cmds, pToks);

  // 2. fold Cf[n'][e] = sum_h Wif[n'][h] * W_prj[h][e]
  launch_gemm(stream, dnWif, pWprjT, nullptr, pCf, 768, 320, 512, 512, 512, 512, 0, 0);
  launch_gemm(stream, dnWib, pWprjT, nullptr, pCb, 768, 320, 512, 512, 512, 512, 0, 0);

  // 3+4. per-dir: vocab table (f32) then 16 dn GEMM-steps
  for (int dir = 0; dir < 2; ++dir){
    launch_gemm(stream, emb, dir? pCb : pCf, dir? dnbib : dnbif, pT,
                20000, 768, 320, 300, 300, 320, 1, 0);
    const __bf16* Whi = dir? pWhBhi : pWhFhi;
    const __bf16* Wlo = dir? pWhBlo : pWhFlo;
    const float*  bh  = dir? dnbhb  : dnbhf;
    const int*    tks = pToks + (size_t)dir*16*11264;
    for (int s = 0; s < 16; ++s){
      __bf16 *shi, *slo, *dhi, *dlo;
      if ((s & 1) == 0){ shi=pH0hi; slo=pH0lo; dhi=pH1hi; dlo=pH1lo; }
      else             { shi=pH1hi; slo=pH1lo; dhi=pH0hi; dlo=pH0lo; }
      dn_step<<<dim3(176,4), 256, 0, stream>>>(shi, slo, dhi, dlo,
          Whi, Wlo, bh, pT, tks, pSeqh, s, dir);
    }
  }

  // 5. graph encoding (scratch now aliases pT — T is dead)
  k_wsum<<<1024, 256, 0, stream>>>(pSeqh, pWsum);
  k_rowsum<<<1024, 64, 0, stream>>>(pSeqh, pRs);
  launch_gemm(stream, pSeqh,                   pWeT, nullptr, pE1, 1024, 512, 512, 512, 512, 512, 0, 0);
  launch_gemm(stream, pSeqh + (size_t)1024*512,pWlT, nullptr, pE2, 1024, 512, 512, 512, 512, 512, 0, 0);
  launch_gemm(stream, pWsum,                   pWwT, nullptr, pE3, 1024, 512, 512, 512, 512, 512, 0, 0);
  k_combine<<<2048, 256, 0, stream>>>(pE1, pE2, pE3, pRs, pY);
  launch_gemm(stream, pY, Wg, bg, pGe, 1024, 512, 512, 512, 512, 512, 2, 0);
  // 6. diff GRU input transforms (bf16 out)
  launch_gemm(stream, pGe, dWif, dbif, pXf, 1024, 1536, 512, 512, 512, 512, 1, 1);
  launch_gemm(stream, pGe, dWib, dbib, pXb, 1024, 1536, 512, 512, 512, 512, 1, 1);
  // 7. scoring
  launch_gemm(stream, pSeqh + (size_t)10240*512, Wa1, nullptr, pAmat, 1024, 1024, 512, 512, 512, 1024, 0, 0);
  launch_gemm(stream, pGe, Wa1 + 512, ba1, pGmat, 1024, 1024, 512, 512, 512, 1024, 1, 0);
  k_score<<<1024, 256, 0, stream>>>(pAmat, pGmat, Wa2, ba2, pScf);
  // 8. diff BiGRU: 64 serial micro-launches
  hipMemsetAsync(pHA, 0, 32*512*sizeof(float), stream);
  float* ha = pHA; float* hb = pHB;
  for (int t=0; t<64; ++t){
    diff_step<<<16, 256, 0, stream>>>(ha, hb, pdWhF, pdWhB, dbhf, dbhb, pXf, pXb, t);
    float* tmp = ha; ha = hb; hb = tmp;
  }
  // 9. outputs
  k_final<<<16, 64, 0, stream>>>(pScf, cmds, ha, Wc, bc, (float*)d_out);
}